// Round 6
// baseline (264.588 us; speedup 1.0000x reference)
//
#include <hip/hip_runtime.h>
#include <hip/hip_bf16.h>
#include <stdint.h>

#define NROWS 65536
#define DFEAT 256

typedef __bf16 bf16x8 __attribute__((ext_vector_type(8)));
typedef float f32x4 __attribute__((ext_vector_type(4)));

__device__ __forceinline__ float fast_tanh(float x) {
    return 1.0f - 2.0f / (__expf(2.0f * x) + 1.0f);
}

// ---------------------------------------------------------------------------
// K1 (merged, all parts independent):
//   blocks [0,512):    per-column sum/sumsq of x (atomics into zeroed ws)
//   blocks [512,1024): P = Wf@W2 [256,512], K=2048, split-K=4, fp32 atomics
//   blocks [1024,1536): u = W2@b1 + b2 [2048]
// ---------------------------------------------------------------------------
__global__ void k1_kernel(const float4* __restrict__ x4,
                          float* __restrict__ sums,
                          float* __restrict__ sumsq,
                          const float* __restrict__ Wf,
                          const float* __restrict__ W2,
                          const float* __restrict__ b1,
                          const float* __restrict__ b2,
                          float* __restrict__ P,
                          float* __restrict__ u) {
    __shared__ float smem[2176];
    int t = threadIdx.x;
    int b = blockIdx.x;
    if (b < 512) {
        // ---- stats ----
        float (*ps)[256] = (float (*)[256])smem;          // [4][256]
        float (*pq)[256] = (float (*)[256])(smem + 1024); // [4][256]
        int c4 = t & 63;
        int r  = t >> 6;
        size_t i0 = (size_t)b * 128;
        float4 s = make_float4(0.f, 0.f, 0.f, 0.f);
        float4 q = make_float4(0.f, 0.f, 0.f, 0.f);
        for (int i = r; i < 128; i += 4) {
            float4 v = x4[(i0 + i) * 64 + c4];
            s.x += v.x; s.y += v.y; s.z += v.z; s.w += v.w;
            q.x += v.x * v.x; q.y += v.y * v.y; q.z += v.z * v.z; q.w += v.w * v.w;
        }
        ps[r][c4 * 4 + 0] = s.x; ps[r][c4 * 4 + 1] = s.y;
        ps[r][c4 * 4 + 2] = s.z; ps[r][c4 * 4 + 3] = s.w;
        pq[r][c4 * 4 + 0] = q.x; pq[r][c4 * 4 + 1] = q.y;
        pq[r][c4 * 4 + 2] = q.z; pq[r][c4 * 4 + 3] = q.w;
        __syncthreads();
        float ts = ps[0][t] + ps[1][t] + ps[2][t] + ps[3][t];
        float tq = pq[0][t] + pq[1][t] + pq[2][t] + pq[3][t];
        atomicAdd(&sums[t], ts);
        atomicAdd(&sumsq[t], tq);
    } else if (b < 1024) {
        // ---- P = Wf@W2, split-K ----
        int bb = b - 512;
        int bj = (bb & 15) * 32;        // N dim (512)
        int bi = ((bb >> 4) & 7) * 32;  // M dim (256)
        int kb = (bb >> 7) * 512;       // K chunk
        float (*As)[33] = (float (*)[33])smem;          // [32][33]
        float (*Bs)[33] = (float (*)[33])(smem + 1056); // [32][33]
        int tx = t & 15, ty = t >> 4;
        int row = t >> 3;
        int col = (t & 7) * 4;
        float acc00 = 0.f, acc01 = 0.f, acc10 = 0.f, acc11 = 0.f;
        for (int k0 = kb; k0 < kb + 512; k0 += 32) {
            float4 av = *(const float4*)&Wf[(size_t)(bi + row) * 2048 + k0 + col];
            As[row][col + 0] = av.x; As[row][col + 1] = av.y;
            As[row][col + 2] = av.z; As[row][col + 3] = av.w;
            float4 bv = *(const float4*)&W2[(size_t)(k0 + row) * 512 + bj + col];
            Bs[row][col + 0] = bv.x; Bs[row][col + 1] = bv.y;
            Bs[row][col + 2] = bv.z; Bs[row][col + 3] = bv.w;
            __syncthreads();
            #pragma unroll
            for (int k = 0; k < 32; ++k) {
                float a0 = As[ty * 2 + 0][k];
                float a1 = As[ty * 2 + 1][k];
                float b0 = Bs[k][tx * 2 + 0];
                float b1v = Bs[k][tx * 2 + 1];
                acc00 += a0 * b0; acc01 += a0 * b1v;
                acc10 += a1 * b0; acc11 += a1 * b1v;
            }
            __syncthreads();
        }
        int i = bi + ty * 2, j = bj + tx * 2;
        atomicAdd(&P[(size_t)(i + 0) * 512 + j + 0], acc00);
        atomicAdd(&P[(size_t)(i + 0) * 512 + j + 1], acc01);
        atomicAdd(&P[(size_t)(i + 1) * 512 + j + 0], acc10);
        atomicAdd(&P[(size_t)(i + 1) * 512 + j + 1], acc11);
    } else {
        // ---- u = W2@b1 + b2 ----
        int lane = t & 63;
        int row = (b - 1024) * 4 + (t >> 6);
        const float* Wr = W2 + (size_t)row * 512;
        float s = 0.f;
        for (int k = lane; k < 512; k += 64) s += Wr[k] * b1[k];
        #pragma unroll
        for (int off = 32; off; off >>= 1) s += __shfl_xor(s, off);
        if (lane == 0) u[row] = s + b2[row];
    }
}

// ---------------------------------------------------------------------------
// K2 (merged, all parts depend only on K1):
//   blocks [0,64):   M = P@W1, epilogue -> bf16 hi/lo Bprep[8][2][4][256][8]
//   blocks [64,128): cv = Wf@u + bf
//   block 128:       finalize BN -> scl/sft
// ---------------------------------------------------------------------------
__global__ void k2_kernel(const float* __restrict__ sums,
                          const float* __restrict__ sumsq,
                          const float* __restrict__ gamma,
                          const float* __restrict__ beta,
                          float* __restrict__ scl,
                          float* __restrict__ sft,
                          const float* __restrict__ P,
                          const float* __restrict__ W1,
                          const float* __restrict__ Wf,
                          const float* __restrict__ u,
                          const float* __restrict__ bfv,
                          __bf16* __restrict__ Bprep,
                          float* __restrict__ cv) {
    __shared__ float smem[2176];
    int t = threadIdx.x;
    int b = blockIdx.x;
    if (b >= 128) {
        const float invN = 1.0f / (float)NROWS;
        float mu  = sums[t] * invN;
        float var = sumsq[t] * invN - mu * mu;
        float rs  = rsqrtf(var + 1e-5f);
        float a   = gamma[t] * rs;
        scl[t] = a;
        sft[t] = beta[t] - mu * a;
        return;
    }
    if (b >= 64) {
        int lane = t & 63;
        int row = (b - 64) * 4 + (t >> 6);
        const float* Wr = Wf + (size_t)row * 2048;
        float s = 0.f;
        for (int k = lane; k < 2048; k += 64) s += Wr[k] * u[k];
        #pragma unroll
        for (int off = 32; off; off >>= 1) s += __shfl_xor(s, off);
        if (lane == 0) cv[row] = s + bfv[row];
        return;
    }
    // ---- M tile + Bprep ----
    float (*As)[33] = (float (*)[33])smem;
    float (*Bs)[33] = (float (*)[33])(smem + 1056);
    int tx = t & 15, ty = t >> 4;
    int bi = (b >> 3) * 32;   // j-dim of M (output col of main GEMM)
    int bj = (b & 7) * 32;    // k-dim of M
    int row = t >> 3;
    int col = (t & 7) * 4;
    float acc00 = 0.f, acc01 = 0.f, acc10 = 0.f, acc11 = 0.f;
    for (int k0 = 0; k0 < 512; k0 += 32) {
        float4 av = *(const float4*)&P[(size_t)(bi + row) * 512 + k0 + col];
        As[row][col + 0] = av.x; As[row][col + 1] = av.y;
        As[row][col + 2] = av.z; As[row][col + 3] = av.w;
        float4 bv = *(const float4*)&W1[(size_t)(k0 + row) * 256 + bj + col];
        Bs[row][col + 0] = bv.x; Bs[row][col + 1] = bv.y;
        Bs[row][col + 2] = bv.z; Bs[row][col + 3] = bv.w;
        __syncthreads();
        #pragma unroll
        for (int k = 0; k < 32; ++k) {
            float a0 = As[ty * 2 + 0][k];
            float a1 = As[ty * 2 + 1][k];
            float b0 = Bs[k][tx * 2 + 0];
            float b1v = Bs[k][tx * 2 + 1];
            acc00 += a0 * b0; acc01 += a0 * b1v;
            acc10 += a1 * b0; acc11 += a1 * b1v;
        }
        __syncthreads();
    }
    int j = bi + ty * 2, k = bj + tx * 2;
    float vals[2][2] = {{acc00, acc01}, {acc10, acc11}};
    #pragma unroll
    for (int dj = 0; dj < 2; ++dj)
        #pragma unroll
        for (int dk = 0; dk < 2; ++dk) {
            float v = vals[dj][dk];
            int jj = j + dj, kk = k + dk;
            __bf16 h = (__bf16)v;
            __bf16 lo = (__bf16)(v - (float)h);
            int kstep = kk >> 5, kgrp = (kk >> 3) & 3, e = kk & 7;
            Bprep[((((size_t)kstep * 2 + 0) * 4 + kgrp) * 256 + jj) * 8 + e] = h;
            Bprep[((((size_t)kstep * 2 + 1) * 4 + kgrp) * 256 + jj) * 8 + e] = lo;
        }
}

// ---------------------------------------------------------------------------
// Main: fused BN + raw_feats + split-bf16 MFMA GEMM + tanh. PIPELINED:
//  - A-LDS double-buffered -> ONE barrier per K-step (write buf[s&1] at s+2
//    is safe: every wave passed barrier(s+1), which follows its MFMA reads
//    of buf[s&1] at step s in program order).
//  - x for step s+1 register-prefetched before barrier(s) -> HBM latency
//    spans the MFMA block.
//  - scl/sft staged once in LDS (broadcast reads, no vmcnt on A critical path).
//  - B fragments direct from global (Bprep 256 KB, L2-resident).
// 3 passes: xh@Mh + xl@Mh + xh@Ml (xl@Ml ~2^-18, dropped).
// ---------------------------------------------------------------------------
__global__ __launch_bounds__(256, 4)
void main_mfma(const float4* __restrict__ x4,
               const float* __restrict__ scl,
               const float* __restrict__ sft,
               const __bf16* __restrict__ Bprep,
               const float* __restrict__ cvec,
               float* __restrict__ out,
               float4* __restrict__ rf4) {
    __shared__ __align__(16) __bf16 Abuf[2][2][64][4][8];   // [dbuf][var][row][kgrp][8] = 16 KB
    __shared__ float ss[256], sh[256];
    int t = threadIdx.x;
    int l = t & 63;
    int w = t >> 6;
    int g = l >> 4, li = l & 15;
    size_t row0 = (size_t)blockIdx.x * 64;
    int arow = t >> 2;   // staging row 0..63
    int akg  = t & 3;    // staging kgrp 0..3

    ss[t] = scl[t];
    sh[t] = sft[t];

    f32x4 acc[4][4];
    #pragma unroll
    for (int i = 0; i < 4; ++i)
        #pragma unroll
        for (int j = 0; j < 4; ++j)
            acc[i][j] = (f32x4){0.f, 0.f, 0.f, 0.f};

    // prefetch x for step 0
    size_t xb = (row0 + arow) * 64 + akg * 2;
    float4 v0 = x4[xb];
    float4 v1 = x4[xb + 1];

    __syncthreads();   // ss/sh visible

    #pragma unroll 2
    for (int s = 0; s < 8; ++s) {
        // --- A stage: BN + tanh->rf + hi/lo split -> LDS buf[s&1] ---
        int kb = s * 32 + akg * 8;
        float4 sc0 = *(const float4*)&ss[kb], sc1 = *(const float4*)&ss[kb + 4];
        float4 sf0 = *(const float4*)&sh[kb], sf1 = *(const float4*)&sh[kb + 4];
        float xn[8];
        xn[0] = v0.x * sc0.x + sf0.x;
        xn[1] = v0.y * sc0.y + sf0.y;
        xn[2] = v0.z * sc0.z + sf0.z;
        xn[3] = v0.w * sc0.w + sf0.w;
        xn[4] = v1.x * sc1.x + sf1.x;
        xn[5] = v1.y * sc1.y + sf1.y;
        xn[6] = v1.z * sc1.z + sf1.z;
        xn[7] = v1.w * sc1.w + sf1.w;
        float4 r0, r1;
        r0.x = fast_tanh(xn[0]); r0.y = fast_tanh(xn[1]);
        r0.z = fast_tanh(xn[2]); r0.w = fast_tanh(xn[3]);
        r1.x = fast_tanh(xn[4]); r1.y = fast_tanh(xn[5]);
        r1.z = fast_tanh(xn[6]); r1.w = fast_tanh(xn[7]);
        rf4[xb + s * 8] = r0;
        rf4[xb + s * 8 + 1] = r1;
        bf16x8 hv, lv;
        #pragma unroll
        for (int e = 0; e < 8; ++e) {
            __bf16 h = (__bf16)xn[e];
            hv[e] = h;
            lv[e] = (__bf16)(xn[e] - (float)h);
        }
        *(bf16x8*)&Abuf[s & 1][0][arow][akg][0] = hv;
        *(bf16x8*)&Abuf[s & 1][1][arow][akg][0] = lv;
        // --- prefetch x for step s+1 (latency spans barrier + MFMA) ---
        if (s < 7) {
            v0 = x4[xb + (s + 1) * 8];
            v1 = x4[xb + (s + 1) * 8 + 1];
        }
        __syncthreads();

        // --- A fragments from LDS ---
        bf16x8 ah[4], al[4];
        #pragma unroll
        for (int i = 0; i < 4; ++i) {
            ah[i] = *(const bf16x8*)&Abuf[s & 1][0][i * 16 + li][g][0];
            al[i] = *(const bf16x8*)&Abuf[s & 1][1][i * 16 + li][g][0];
        }
        // --- B fragments direct from global (L2-resident), then MFMA ---
        const __bf16* bh_base = Bprep + (size_t)(8 * s + g) * 2048;
        const __bf16* bl_base = Bprep + (size_t)(8 * s + 4 + g) * 2048;
        #pragma unroll
        for (int j = 0; j < 4; ++j) {
            int coll = w * 64 + j * 16 + li;
            bf16x8 bh = *(const bf16x8*)&bh_base[(size_t)coll * 8];
            bf16x8 bl = *(const bf16x8*)&bl_base[(size_t)coll * 8];
            #pragma unroll
            for (int i = 0; i < 4; ++i) {
                acc[i][j] = __builtin_amdgcn_mfma_f32_16x16x32_bf16(ah[i], bh, acc[i][j], 0, 0, 0);
                acc[i][j] = __builtin_amdgcn_mfma_f32_16x16x32_bf16(al[i], bh, acc[i][j], 0, 0, 0);
                acc[i][j] = __builtin_amdgcn_mfma_f32_16x16x32_bf16(ah[i], bl, acc[i][j], 0, 0, 0);
            }
        }
        // no second barrier: next iteration writes the OTHER Abuf half
    }

    // --- epilogue: out = tanh(acc + c); C/D map col=lane&15, row=(lane>>4)*4+reg ---
    #pragma unroll
    for (int j = 0; j < 4; ++j) {
        int gcol = w * 64 + j * 16 + li;
        float cj = cvec[gcol];
        #pragma unroll
        for (int i = 0; i < 4; ++i) {
            #pragma unroll
            for (int r = 0; r < 4; ++r) {
                size_t grow = row0 + i * 16 + g * 4 + r;
                out[grow * 256 + gcol] = fast_tanh(acc[i][j][r] + cj);
            }
        }
    }
}

// ---------------------------------------------------------------------------
// ws layout (floats):
//   [0]      sums   256      (zeroed)
//   [256]    sumsq  256      (zeroed)
//   [512]    P      131072   (zeroed: atomic split-K target)
//   [131584] u      2048
//   [133632] cv     256
//   [133888] scl    256
//   [134144] sft    256
//   [134400] Bprep  (__bf16, 131072 elems = 65536 float slots)
// total 199936 floats ~= 800 KB.
// ---------------------------------------------------------------------------
extern "C" void kernel_launch(void* const* d_in, const int* in_sizes, int n_in,
                              void* d_out, int out_size, void* d_ws, size_t ws_size,
                              hipStream_t stream) {
    const float* x     = (const float*)d_in[0];
    const float* gamma = (const float*)d_in[1];
    const float* beta  = (const float*)d_in[2];
    const float* W1    = (const float*)d_in[3];
    const float* b1    = (const float*)d_in[4];
    const float* W2    = (const float*)d_in[5];
    const float* b2    = (const float*)d_in[6];
    const float* Wf    = (const float*)d_in[7];
    const float* bf    = (const float*)d_in[8];

    float* out = (float*)d_out;                    // [65536,256]
    float* rf  = out + (size_t)NROWS * DFEAT;      // [65536,256]

    float* ws    = (float*)d_ws;
    float* sums  = ws;
    float* sumsq = ws + 256;
    float* P     = ws + 512;
    float* u     = ws + 131584;
    float* cv    = ws + 133632;
    float* scl   = ws + 133888;
    float* sft   = ws + 134144;
    __bf16* Bprep = (__bf16*)(ws + 134400);

    // zero atomic targets: sums, sumsq, P
    hipMemsetAsync(ws, 0, (size_t)131584 * sizeof(float), stream);

    k1_kernel<<<1536, 256, 0, stream>>>((const float4*)x, sums, sumsq,
                                        Wf, W2, b1, b2, P, u);
    k2_kernel<<<129, 256, 0, stream>>>(sums, sumsq, gamma, beta, scl, sft,
                                       P, W1, Wf, u, bf, Bprep, cv);
    main_mfma<<<NROWS / 64, 256, 0, stream>>>((const float4*)x, scl, sft,
                                              Bprep, cv, out, (float4*)rf);
}